// Round 5
// baseline (188.053 us; speedup 1.0000x reference)
//
#include <hip/hip_runtime.h>

typedef float f32x4 __attribute__((ext_vector_type(4)));
typedef __bf16 bf16x8 __attribute__((ext_vector_type(8)));
typedef __bf16 bf16x2 __attribute__((ext_vector_type(2)));

#define LDT 68
#define NITER 4
#define TWO_LOG2E 2.8853900817779268f

__device__ __forceinline__ unsigned short bf16_bits(float f) {
    return __builtin_bit_cast(unsigned short, (__bf16)f);
}
__device__ __forceinline__ unsigned pk2(float a, float b) {
    bf16x2 t; t[0] = (__bf16)a; t[1] = (__bf16)b;
    return __builtin_bit_cast(unsigned, t);
}
// tanh(v + b1) with bias pre-scaled: tb = 2*log2e*b1
// tanh(y) = 1 - 2/(e^{2y}+1) = 1 - 2*rcp(exp2(2*log2e*v + tb) + 1)
__device__ __forceinline__ float tanh_b(float v, float tb) {
    float e = __builtin_amdgcn_exp2f(fmaf(TWO_LOG2E, v, tb));
    float r = __builtin_amdgcn_rcpf(e + 1.0f);
    return fmaf(-2.0f, r, 1.0f);
}

// ---------------------------------------------------------------------------
// Precompute: T = I + 0.02A; M = T^50 via 7 LDS matmuls (fp32, 4x4 tiles,
// transposed-copy trick: store Z and Z^T so both operands read as b128).
// Then ws[0..16383] = W1p = M@W1 as GEMM1 B-frags (bf16),
//      ws[16384..20479] = W2 as GEMM2 B-frags (bf16, k-permuted).
// 1 block, 1024 threads (matmul chain uses first 256).
// ---------------------------------------------------------------------------
__global__ __launch_bounds__(1024) void ode_precompute(
        const float* __restrict__ A, const float* __restrict__ W1,
        const float* __restrict__ W2, unsigned short* __restrict__ ws) {
    __shared__ float Ts[64 * LDT];
    __shared__ float Za[64 * LDT];
    __shared__ float ZaT[64 * LDT];
    __shared__ float Zb[64 * LDT];
    __shared__ float ZbT[64 * LDT];
    const int t = threadIdx.x;

    for (int i = t; i < 4096; i += 1024) {
        int r = i >> 6, c = i & 63;
        float v = 0.02f * A[i] + ((r == c) ? 1.0f : 0.0f);
        Ts[r * LDT + c] = v;
        Za[r * LDT + c] = v;
        ZaT[c * LDT + r] = v;
    }
    __syncthreads();

    const int r0 = ((t >> 4) & 15) * 4;
    const int c0 = (t & 15) * 4;
    auto mm = [&](const float* XT, const float* Y, float* Z, float* ZT) {
        if (t < 256) {
            float ac[4][4];
            #pragma unroll
            for (int i = 0; i < 4; i++)
                #pragma unroll
                for (int j = 0; j < 4; j++) ac[i][j] = 0.0f;
            #pragma unroll 8
            for (int k = 0; k < 64; k++) {
                float4 a = *(const float4*)(XT + k * LDT + r0);  // X[r0..r0+3][k]
                float4 b = *(const float4*)(Y + k * LDT + c0);   // Y[k][c0..c0+3]
                ac[0][0] = fmaf(a.x, b.x, ac[0][0]); ac[0][1] = fmaf(a.x, b.y, ac[0][1]);
                ac[0][2] = fmaf(a.x, b.z, ac[0][2]); ac[0][3] = fmaf(a.x, b.w, ac[0][3]);
                ac[1][0] = fmaf(a.y, b.x, ac[1][0]); ac[1][1] = fmaf(a.y, b.y, ac[1][1]);
                ac[1][2] = fmaf(a.y, b.z, ac[1][2]); ac[1][3] = fmaf(a.y, b.w, ac[1][3]);
                ac[2][0] = fmaf(a.z, b.x, ac[2][0]); ac[2][1] = fmaf(a.z, b.y, ac[2][1]);
                ac[2][2] = fmaf(a.z, b.z, ac[2][2]); ac[2][3] = fmaf(a.z, b.w, ac[2][3]);
                ac[3][0] = fmaf(a.w, b.x, ac[3][0]); ac[3][1] = fmaf(a.w, b.y, ac[3][1]);
                ac[3][2] = fmaf(a.w, b.z, ac[3][2]); ac[3][3] = fmaf(a.w, b.w, ac[3][3]);
            }
            #pragma unroll
            for (int i = 0; i < 4; i++)
                *(float4*)(Z + (r0 + i) * LDT + c0) =
                    make_float4(ac[i][0], ac[i][1], ac[i][2], ac[i][3]);
            #pragma unroll
            for (int j = 0; j < 4; j++)
                *(float4*)(ZT + (c0 + j) * LDT + r0) =
                    make_float4(ac[0][j], ac[1][j], ac[2][j], ac[3][j]);
        }
        __syncthreads();
    };
    // 50 = 0b110010 -> sq, *T, sq, sq, sq, *T, sq  (result in Zb)
    mm(ZaT, Za, Zb, ZbT);  // T^2
    mm(ZbT, Ts, Za, ZaT);  // T^3
    mm(ZaT, Za, Zb, ZbT);  // T^6
    mm(ZbT, Zb, Za, ZaT);  // T^12
    mm(ZaT, Za, Zb, ZbT);  // T^24
    mm(ZbT, Ts, Za, ZaT);  // T^25
    mm(ZaT, Za, Zb, ZbT);  // T^50 -> Zb

    // W1p: thread (k = t>>4, jb = t&15) computes row k, cols 16*jb .. 16*jb+15
    {
        const int k = t >> 4;
        const int jb = t & 15;
        float acc[16];
        #pragma unroll
        for (int u = 0; u < 16; u++) acc[u] = 0.0f;
        const float* trow = Zb + k * LDT;
        for (int d = 0; d < 64; d++) {
            float a = trow[d];
            const float4* wr = (const float4*)(W1 + d * 256 + jb * 16);
            float4 w0 = wr[0], w1v = wr[1], w2v = wr[2], w3v = wr[3];
            acc[0]  = fmaf(a, w0.x,  acc[0]);  acc[1]  = fmaf(a, w0.y,  acc[1]);
            acc[2]  = fmaf(a, w0.z,  acc[2]);  acc[3]  = fmaf(a, w0.w,  acc[3]);
            acc[4]  = fmaf(a, w1v.x, acc[4]);  acc[5]  = fmaf(a, w1v.y, acc[5]);
            acc[6]  = fmaf(a, w1v.z, acc[6]);  acc[7]  = fmaf(a, w1v.w, acc[7]);
            acc[8]  = fmaf(a, w2v.x, acc[8]);  acc[9]  = fmaf(a, w2v.y, acc[9]);
            acc[10] = fmaf(a, w2v.z, acc[10]); acc[11] = fmaf(a, w2v.w, acc[11]);
            acc[12] = fmaf(a, w3v.x, acc[12]); acc[13] = fmaf(a, w3v.y, acc[13]);
            acc[14] = fmaf(a, w3v.z, acc[14]); acc[15] = fmaf(a, w3v.w, acc[15]);
        }
        const int kt = k >> 5, qq = (k >> 3) & 3, jj = k & 7;
        #pragma unroll
        for (int u = 0; u < 16; u++)
            ws[(((jb * 2 + kt) * 64) + qq * 16 + u) * 8 + jj] = bf16_bits(acc[u]);
    }
    // W2 fragments (4096 elems, 4 per thread); k' = 64pp + 4c + nt4
    #pragma unroll
    for (int e = 0; e < 4; e++) {
        int f = t * 4 + e;
        int kt2 = f >> 9, l = (f >> 3) & 63, j2 = f & 7;
        int kp = 32 * kt2 + 8 * (l >> 4) + j2;
        int row = 64 * (kp >> 6) + 16 * (kp & 3) + ((kp >> 2) & 15);
        ws[16384 + f] = bf16_bits(W2[row * 16 + (l & 15)]);
    }
}

// ---------------------------------------------------------------------------
// Main: out = tanh(x @ W1p + b1) @ W2 + b2, MFMA bf16.
// 512 threads (8 waves), 32 rows/wave/chunk, NITER=4 chunks per block with
// rolling x prefetch (next chunk's loads issued before current compute).
// ---------------------------------------------------------------------------
__global__ __launch_bounds__(512, 4) void ode_main(
        const float* __restrict__ x, const unsigned short* __restrict__ wsfrag,
        const float* __restrict__ b1, const float* __restrict__ b2,
        float* __restrict__ out, int B) {
    __shared__ unsigned short w1f[16384];       // 32KB
    __shared__ unsigned short w2f[4096];        // 8KB
    __shared__ float b1s2[256];                 // 1KB (pre-scaled 2*log2e*b1)
    __shared__ unsigned hbuf[8 * 2 * 16 * 36];  // 36KB (wave-private chunks)
    const int t = threadIdx.x;
    {
        const uint4* src = (const uint4*)wsfrag;  // 2560 uint4
        uint4* d1 = (uint4*)w1f;
        #pragma unroll
        for (int i = 0; i < 4; i++) d1[t + 512 * i] = src[t + 512 * i];
        ((uint4*)w2f)[t] = src[2048 + t];
        if (t < 64) {
            float4 bb = ((const float4*)b1)[t];
            bb.x *= TWO_LOG2E; bb.y *= TWO_LOG2E; bb.z *= TWO_LOG2E; bb.w *= TWO_LOG2E;
            ((float4*)b1s2)[t] = bb;
        }
    }
    __syncthreads();

    const int wid = t >> 6, lane = t & 63;
    const int q = lane >> 4, c = lane & 15;
    unsigned* hw = hbuf + wid * (2 * 16 * 36);
    const float b2v = b2[c];
    const long blockbase = (long)blockIdx.x * (256 * NITER);

    // ---- prefetch chunk 0
    float4 xraw[8];  // [s*4 + kt*2 + half]
    {
        long nb = blockbase + wid * 32;
        #pragma unroll
        for (int s = 0; s < 2; s++) {
            long row = nb + 16 * s + c;
            if (row >= B) row = B - 1;
            const float* xp = x + row * 64;
            xraw[s * 4 + 0] = *(const float4*)(xp + q * 8);
            xraw[s * 4 + 1] = *(const float4*)(xp + q * 8 + 4);
            xraw[s * 4 + 2] = *(const float4*)(xp + 32 + q * 8);
            xraw[s * 4 + 3] = *(const float4*)(xp + 32 + q * 8 + 4);
        }
    }

    #pragma unroll 1
    for (int it = 0; it < NITER; ++it) {
        const long rowbase = blockbase + it * 256 + wid * 32;
        // ---- convert current chunk to bf16 fragments
        bf16x8 xb[2][2];
        #pragma unroll
        for (int s = 0; s < 2; s++)
            #pragma unroll
            for (int kt = 0; kt < 2; kt++) {
                float4 u0 = xraw[s * 4 + kt * 2];
                float4 u1 = xraw[s * 4 + kt * 2 + 1];
                bf16x8 cv;
                cv[0] = (__bf16)u0.x; cv[1] = (__bf16)u0.y;
                cv[2] = (__bf16)u0.z; cv[3] = (__bf16)u0.w;
                cv[4] = (__bf16)u1.x; cv[5] = (__bf16)u1.y;
                cv[6] = (__bf16)u1.z; cv[7] = (__bf16)u1.w;
                xb[s][kt] = cv;
            }
        // ---- issue next chunk's loads (land under this chunk's compute)
        if (it + 1 < NITER) {
            long nb = rowbase + 256;
            #pragma unroll
            for (int s = 0; s < 2; s++) {
                long row = nb + 16 * s + c;
                if (row >= B) row = B - 1;
                const float* xp = x + row * 64;
                xraw[s * 4 + 0] = *(const float4*)(xp + q * 8);
                xraw[s * 4 + 1] = *(const float4*)(xp + q * 8 + 4);
                xraw[s * 4 + 2] = *(const float4*)(xp + 32 + q * 8);
                xraw[s * 4 + 3] = *(const float4*)(xp + 32 + q * 8 + 4);
            }
        }

        f32x4 oacc[2] = {{0, 0, 0, 0}, {0, 0, 0, 0}};
        #pragma unroll
        for (int pp = 0; pp < 4; pp++) {
            // ---- GEMM1: 4 ntiles x 2 strips (no bias in acc; folded into tanh)
            f32x4 acc[2][4];
            #pragma unroll
            for (int n4 = 0; n4 < 4; n4++) {
                acc[0][n4] = (f32x4){0.0f, 0.0f, 0.0f, 0.0f};
                acc[1][n4] = (f32x4){0.0f, 0.0f, 0.0f, 0.0f};
            }
            #pragma unroll
            for (int kt = 0; kt < 2; kt++) {
                bf16x8 wv[4];
                #pragma unroll
                for (int n4 = 0; n4 < 4; n4++) {
                    uint4 wraw = *(const uint4*)(w1f + (((4 * pp + n4) * 2 + kt) * 64 + lane) * 8);
                    wv[n4] = __builtin_bit_cast(bf16x8, wraw);
                }
                #pragma unroll
                for (int s = 0; s < 2; s++) {
                    #pragma unroll
                    for (int n4 = 0; n4 < 4; n4++)
                        acc[s][n4] = __builtin_amdgcn_mfma_f32_16x16x32_bf16(xb[s][kt], wv[n4], acc[s][n4], 0, 0, 0);
                }
            }
            float tb[4];
            #pragma unroll
            for (int n4 = 0; n4 < 4; n4++) tb[n4] = b1s2[(4 * pp + n4) * 16 + c];
            // ---- tanh (+bias) + pack + b64 write to wave-private h chunk
            #pragma unroll
            for (int s = 0; s < 2; s++) {
                #pragma unroll
                for (int r = 0; r < 4; r++) {
                    float h0 = tanh_b(acc[s][0][r], tb[0]);
                    float h1 = tanh_b(acc[s][1][r], tb[1]);
                    float h2 = tanh_b(acc[s][2][r], tb[2]);
                    float h3 = tanh_b(acc[s][3][r], tb[3]);
                    uint2 wp;
                    wp.x = pk2(h0, h1);
                    wp.y = pk2(h2, h3);
                    *(uint2*)(hw + (s * 16 + 4 * q + r) * 36 + 2 * c) = wp;
                }
            }
            // ---- GEMM2: 2 ktiles of this pp-chunk
            #pragma unroll
            for (int tt = 0; tt < 2; tt++) {
                uint4 w2raw = *(const uint4*)(w2f + ((2 * pp + tt) * 64 + lane) * 8);
                bf16x8 bw2 = __builtin_bit_cast(bf16x8, w2raw);
                #pragma unroll
                for (int s = 0; s < 2; s++) {
                    uint4 hraw = *(const uint4*)(hw + (s * 16 + c) * 36 + tt * 16 + 4 * q);
                    bf16x8 ha = __builtin_bit_cast(bf16x8, hraw);
                    oacc[s] = __builtin_amdgcn_mfma_f32_16x16x32_bf16(ha, bw2, oacc[s], 0, 0, 0);
                }
            }
        }
        // ---- epilogue: transpose via wave-private LDS (stride 18), float4 store
        float* hwf = (float*)hw;
        #pragma unroll
        for (int s = 0; s < 2; s++) {
            #pragma unroll
            for (int r = 0; r < 4; r++)
                hwf[(4 * q + r) * 18 + c] = oacc[s][r] + b2v;
            long row = rowbase + 16 * s + (lane >> 2);
            float4 val = *(const float4*)(hwf + (lane >> 2) * 18 + (lane & 3) * 4);
            if (row < B) *(float4*)(out + row * 16 + (lane & 3) * 4) = val;
        }
    }
}

extern "C" void kernel_launch(void* const* d_in, const int* in_sizes, int n_in,
                              void* d_out, int out_size, void* d_ws, size_t ws_size,
                              hipStream_t stream) {
    const float* x  = (const float*)d_in[0];
    const float* A  = (const float*)d_in[1];
    const float* W1 = (const float*)d_in[2];
    const float* b1 = (const float*)d_in[3];
    const float* W2 = (const float*)d_in[4];
    const float* b2 = (const float*)d_in[5];
    float* out = (float*)d_out;
    unsigned short* ws = (unsigned short*)d_ws;  // 40KB fragment area

    const int B = in_sizes[0] / 64;

    ode_precompute<<<1, 1024, 0, stream>>>(A, W1, W2, ws);
    const int rows_per_block = 256 * NITER;
    const int grid = (B + rows_per_block - 1) / rows_per_block;
    ode_main<<<grid, 512, 0, stream>>>(x, ws, b1, b2, out, B);
}

// Round 6
// 170.772 us; speedup vs baseline: 1.1012x; 1.1012x over previous
//
#include <hip/hip_runtime.h>

typedef float f32x4 __attribute__((ext_vector_type(4)));
typedef __bf16 bf16x8 __attribute__((ext_vector_type(8)));
typedef __bf16 bf16x2 __attribute__((ext_vector_type(2)));

#define LDT 68
#define TWO_LOG2E 2.8853900817779268f

__device__ __forceinline__ unsigned short bf16_bits(float f) {
    return __builtin_bit_cast(unsigned short, (__bf16)f);
}
__device__ __forceinline__ unsigned pk2(float a, float b) {
    bf16x2 t; t[0] = (__bf16)a; t[1] = (__bf16)b;
    return __builtin_bit_cast(unsigned, t);
}
// tanh(v + b1), bias pre-scaled: tb = 2*log2e*b1
// tanh = 1 - 2*rcp(exp2(2*log2e*v + tb) + 1)
__device__ __forceinline__ float tanh_b(float v, float tb) {
    float e = __builtin_amdgcn_exp2f(fmaf(TWO_LOG2E, v, tb));
    float r = __builtin_amdgcn_rcpf(e + 1.0f);
    return fmaf(-2.0f, r, 1.0f);
}

// ---------------------------------------------------------------------------
// Precompute: T = I + 0.02A; M = T^50 via 7 LDS matmuls (fp32, transposed-copy
// trick). Then:
//   ws[0..16383]     : W1p = M@W1, fragment (ntg,kt) at ((ntg*2+kt)*64+lane)*8
//                      value = W1p[32kt+8q+j][16ntg+c]   (lane = 16q+c)
//   ws[16384..20479] : W2 row-permuted GEMM2 B-frags: frag tt at
//                      (tt*64+lane)*8+j = W2[n][c],
//                      n = 128*(tt>>2) + 16*(2*(tt&3)+(j>>2)) + 4q + (j&3)
// 1 block, 1024 threads.
// ---------------------------------------------------------------------------
__global__ __launch_bounds__(1024) void ode_precompute(
        const float* __restrict__ A, const float* __restrict__ W1,
        const float* __restrict__ W2, unsigned short* __restrict__ ws) {
    __shared__ float Ts[64 * LDT];
    __shared__ float Za[64 * LDT];
    __shared__ float ZaT[64 * LDT];
    __shared__ float Zb[64 * LDT];
    __shared__ float ZbT[64 * LDT];
    const int t = threadIdx.x;

    for (int i = t; i < 4096; i += 1024) {
        int r = i >> 6, c = i & 63;
        float v = 0.02f * A[i] + ((r == c) ? 1.0f : 0.0f);
        Ts[r * LDT + c] = v;
        Za[r * LDT + c] = v;
        ZaT[c * LDT + r] = v;
    }
    __syncthreads();

    const int r0 = ((t >> 4) & 15) * 4;
    const int c0 = (t & 15) * 4;
    auto mm = [&](const float* XT, const float* Y, float* Z, float* ZT) {
        if (t < 256) {
            float ac[4][4];
            #pragma unroll
            for (int i = 0; i < 4; i++)
                #pragma unroll
                for (int j = 0; j < 4; j++) ac[i][j] = 0.0f;
            #pragma unroll 8
            for (int k = 0; k < 64; k++) {
                float4 a = *(const float4*)(XT + k * LDT + r0);
                float4 b = *(const float4*)(Y + k * LDT + c0);
                ac[0][0] = fmaf(a.x, b.x, ac[0][0]); ac[0][1] = fmaf(a.x, b.y, ac[0][1]);
                ac[0][2] = fmaf(a.x, b.z, ac[0][2]); ac[0][3] = fmaf(a.x, b.w, ac[0][3]);
                ac[1][0] = fmaf(a.y, b.x, ac[1][0]); ac[1][1] = fmaf(a.y, b.y, ac[1][1]);
                ac[1][2] = fmaf(a.y, b.z, ac[1][2]); ac[1][3] = fmaf(a.y, b.w, ac[1][3]);
                ac[2][0] = fmaf(a.z, b.x, ac[2][0]); ac[2][1] = fmaf(a.z, b.y, ac[2][1]);
                ac[2][2] = fmaf(a.z, b.z, ac[2][2]); ac[2][3] = fmaf(a.z, b.w, ac[2][3]);
                ac[3][0] = fmaf(a.w, b.x, ac[3][0]); ac[3][1] = fmaf(a.w, b.y, ac[3][1]);
                ac[3][2] = fmaf(a.w, b.z, ac[3][2]); ac[3][3] = fmaf(a.w, b.w, ac[3][3]);
            }
            #pragma unroll
            for (int i = 0; i < 4; i++)
                *(float4*)(Z + (r0 + i) * LDT + c0) =
                    make_float4(ac[i][0], ac[i][1], ac[i][2], ac[i][3]);
            #pragma unroll
            for (int j = 0; j < 4; j++)
                *(float4*)(ZT + (c0 + j) * LDT + r0) =
                    make_float4(ac[0][j], ac[1][j], ac[2][j], ac[3][j]);
        }
        __syncthreads();
    };
    // 50 = 0b110010 -> sq, *T, sq, sq, sq, *T, sq  (result in Zb)
    mm(ZaT, Za, Zb, ZbT);  // T^2
    mm(ZbT, Ts, Za, ZaT);  // T^3
    mm(ZaT, Za, Zb, ZbT);  // T^6
    mm(ZbT, Zb, Za, ZaT);  // T^12
    mm(ZaT, Za, Zb, ZbT);  // T^24
    mm(ZbT, Ts, Za, ZaT);  // T^25
    mm(ZaT, Za, Zb, ZbT);  // T^50 -> Zb

    // W1p: thread (k = t>>4, jb = t&15) computes row k, cols 16*jb .. 16*jb+15
    {
        const int k = t >> 4;
        const int jb = t & 15;
        float acc[16];
        #pragma unroll
        for (int u = 0; u < 16; u++) acc[u] = 0.0f;
        const float* trow = Zb + k * LDT;
        for (int d = 0; d < 64; d++) {
            float a = trow[d];
            const float4* wr = (const float4*)(W1 + d * 256 + jb * 16);
            float4 w0 = wr[0], w1v = wr[1], w2v = wr[2], w3v = wr[3];
            acc[0]  = fmaf(a, w0.x,  acc[0]);  acc[1]  = fmaf(a, w0.y,  acc[1]);
            acc[2]  = fmaf(a, w0.z,  acc[2]);  acc[3]  = fmaf(a, w0.w,  acc[3]);
            acc[4]  = fmaf(a, w1v.x, acc[4]);  acc[5]  = fmaf(a, w1v.y, acc[5]);
            acc[6]  = fmaf(a, w1v.z, acc[6]);  acc[7]  = fmaf(a, w1v.w, acc[7]);
            acc[8]  = fmaf(a, w2v.x, acc[8]);  acc[9]  = fmaf(a, w2v.y, acc[9]);
            acc[10] = fmaf(a, w2v.z, acc[10]); acc[11] = fmaf(a, w2v.w, acc[11]);
            acc[12] = fmaf(a, w3v.x, acc[12]); acc[13] = fmaf(a, w3v.y, acc[13]);
            acc[14] = fmaf(a, w3v.z, acc[14]); acc[15] = fmaf(a, w3v.w, acc[15]);
        }
        const int kt = k >> 5, qq = (k >> 3) & 3, jj = k & 7;
        #pragma unroll
        for (int u = 0; u < 16; u++)
            ws[(((jb * 2 + kt) * 64) + qq * 16 + u) * 8 + jj] = bf16_bits(acc[u]);
    }
    // W2 fragments (4096 elems, 4 per thread), new k'-permutation:
    // f = (tt*64+lane)*8+j ; n = 128*(tt>>2) + 16*(2*(tt&3)+(j>>2)) + 4q + (j&3)
    #pragma unroll
    for (int e = 0; e < 4; e++) {
        int f = t * 4 + e;
        int tt = f >> 9, l = (f >> 3) & 63, j = f & 7;
        int qq = l >> 4, cc = l & 15;
        int n = 128 * (tt >> 2) + 16 * (2 * (tt & 3) + (j >> 2)) + 4 * qq + (j & 3);
        ws[16384 + f] = bf16_bits(W2[n * 16 + cc]);
    }
}

// ---------------------------------------------------------------------------
// Main: out = tanh(x @ W1p + b1) @ W2 + b2, MFMA bf16, SWAPPED GEMM1
// (A=W1p-frag, B=x-frag) so h stays entirely in registers — no LDS h
// round-trip, no LDS epilogue. 512 threads (8 waves), 32 rows/wave one-shot.
// LDS = 41KB (w1f 32 + w2f 8 + bias 1) -> 3 blocks/CU by LDS; VGPR<=128.
// ---------------------------------------------------------------------------
__global__ __launch_bounds__(512, 4) void ode_main(
        const float* __restrict__ x, const unsigned short* __restrict__ wsfrag,
        const float* __restrict__ b1, const float* __restrict__ b2,
        float* __restrict__ out, int B) {
    __shared__ unsigned short w1f[16384];  // 32KB
    __shared__ unsigned short w2f[4096];   // 8KB
    __shared__ float b1s2[256];            // 1KB (pre-scaled 2*log2e*b1)
    const int t = threadIdx.x;
    const int wid = t >> 6, lane = t & 63;
    const int q = lane >> 4, c = lane & 15;
    const long rowbase = (long)blockIdx.x * 256 + wid * 32;

    // ---- issue x loads first (latency covered by LDS staging below)
    float4 xraw[8];
    #pragma unroll
    for (int s = 0; s < 2; s++) {
        long row = rowbase + 16 * s + c;
        if (row >= B) row = B - 1;
        const float* xp = x + row * 64 + q * 8;
        xraw[s * 4 + 0] = *(const float4*)(xp);
        xraw[s * 4 + 1] = *(const float4*)(xp + 4);
        xraw[s * 4 + 2] = *(const float4*)(xp + 32);
        xraw[s * 4 + 3] = *(const float4*)(xp + 36);
    }

    // ---- stage weight fragments + scaled bias into LDS
    {
        const uint4* src = (const uint4*)wsfrag;  // 2560 uint4
        uint4* d1 = (uint4*)w1f;
        #pragma unroll
        for (int i = 0; i < 4; i++) d1[t + 512 * i] = src[t + 512 * i];
        ((uint4*)w2f)[t] = src[2048 + t];
        if (t < 64) {
            float4 bb = ((const float4*)b1)[t];
            bb.x *= TWO_LOG2E; bb.y *= TWO_LOG2E; bb.z *= TWO_LOG2E; bb.w *= TWO_LOG2E;
            ((float4*)b1s2)[t] = bb;
        }
    }
    __syncthreads();

    // ---- convert x to bf16 B-fragments: lane (q,c) holds x[row=16s+c][32kt+8q+j]
    bf16x8 xb[2][2];
    #pragma unroll
    for (int s = 0; s < 2; s++)
        #pragma unroll
        for (int kt = 0; kt < 2; kt++) {
            float4 u0 = xraw[s * 4 + kt * 2];
            float4 u1 = xraw[s * 4 + kt * 2 + 1];
            bf16x8 cv;
            cv[0] = (__bf16)u0.x; cv[1] = (__bf16)u0.y;
            cv[2] = (__bf16)u0.z; cv[3] = (__bf16)u0.w;
            cv[4] = (__bf16)u1.x; cv[5] = (__bf16)u1.y;
            cv[6] = (__bf16)u1.z; cv[7] = (__bf16)u1.w;
            xb[s][kt] = cv;
        }

    f32x4 oacc[2] = {{0, 0, 0, 0}, {0, 0, 0, 0}};
    const f32x4 zero4 = {0.0f, 0.0f, 0.0f, 0.0f};

    #pragma unroll
    for (int h = 0; h < 2; h++) {
        // ---- GEMM1 half: 8 ntiles; lane (q,c) acc[s][m][r] = S[16s+c][128h+16m+4q+r]
        f32x4 acc[2][8];
        #pragma unroll
        for (int m = 0; m < 8; m++) {
            const int ntg = 8 * h + m;
            uint4 wr0 = *(const uint4*)(w1f + ((ntg * 2 + 0) * 64 + lane) * 8);
            uint4 wr1 = *(const uint4*)(w1f + ((ntg * 2 + 1) * 64 + lane) * 8);
            bf16x8 wv0 = __builtin_bit_cast(bf16x8, wr0);
            bf16x8 wv1 = __builtin_bit_cast(bf16x8, wr1);
            #pragma unroll
            for (int s = 0; s < 2; s++) {
                f32x4 a = __builtin_amdgcn_mfma_f32_16x16x32_bf16(wv0, xb[s][0], zero4, 0, 0, 0);
                acc[s][m] = __builtin_amdgcn_mfma_f32_16x16x32_bf16(wv1, xb[s][1], a, 0, 0, 0);
            }
        }
        // ---- tanh in-register + GEMM2 (4 ttiles of this half)
        #pragma unroll
        for (int ttl = 0; ttl < 4; ttl++) {
            const int tt = 4 * h + ttl;
            const float* tbp = b1s2 + 128 * h + 32 * ttl + 4 * q;
            float4 tbe = *(const float4*)(tbp);       // bias for m = 2*ttl,   r=0..3
            float4 tbo = *(const float4*)(tbp + 16);  // bias for m = 2*ttl+1, r=0..3
            uint4 w2r = *(const uint4*)(w2f + (tt * 64 + lane) * 8);
            bf16x8 w2v = __builtin_bit_cast(bf16x8, w2r);
            #pragma unroll
            for (int s = 0; s < 2; s++) {
                const f32x4 ae = acc[s][2 * ttl];
                const f32x4 ao = acc[s][2 * ttl + 1];
                uint4 pr;
                pr.x = pk2(tanh_b(ae[0], tbe.x), tanh_b(ae[1], tbe.y));
                pr.y = pk2(tanh_b(ae[2], tbe.z), tanh_b(ae[3], tbe.w));
                pr.z = pk2(tanh_b(ao[0], tbo.x), tanh_b(ao[1], tbo.y));
                pr.w = pk2(tanh_b(ao[2], tbo.z), tanh_b(ao[3], tbo.w));
                bf16x8 pa = __builtin_bit_cast(bf16x8, pr);
                oacc[s] = __builtin_amdgcn_mfma_f32_16x16x32_bf16(pa, w2v, oacc[s], 0, 0, 0);
            }
        }
    }
    // ---- direct store: lane (q,c) holds out[rowbase+16s+4q+r][c]
    const float b2v = b2[c];
    #pragma unroll
    for (int s = 0; s < 2; s++) {
        const long row0 = rowbase + 16 * s + 4 * q;
        #pragma unroll
        for (int r = 0; r < 4; r++) {
            long row = row0 + r;
            if (row < B) out[row * 16 + c] = oacc[s][r] + b2v;
        }
    }
}

extern "C" void kernel_launch(void* const* d_in, const int* in_sizes, int n_in,
                              void* d_out, int out_size, void* d_ws, size_t ws_size,
                              hipStream_t stream) {
    const float* x  = (const float*)d_in[0];
    const float* A  = (const float*)d_in[1];
    const float* W1 = (const float*)d_in[2];
    const float* b1 = (const float*)d_in[3];
    const float* W2 = (const float*)d_in[4];
    const float* b2 = (const float*)d_in[5];
    float* out = (float*)d_out;
    unsigned short* ws = (unsigned short*)d_ws;  // 40KB fragment area

    const int B = in_sizes[0] / 64;

    ode_precompute<<<1, 1024, 0, stream>>>(A, W1, W2, ws);
    const int grid = (B + 255) / 256;
    ode_main<<<grid, 512, 0, stream>>>(x, ws, b1, b2, out, B);
}